// Round 1
// baseline (877.034 us; speedup 1.0000x reference)
//
#include <hip/hip_runtime.h>
#include <hip/hip_bf16.h>
#include <stdint.h>

typedef unsigned short u16;
typedef __attribute__((ext_vector_type(8))) short short8;
typedef __attribute__((ext_vector_type(4))) float f32x4;

#define NB 16384      // batch
#define NH 1024       // hidden
#define NSLOT 49152   // 2*NB routed slots + NB shared ("expert 8") slots
#define LDK 40        // padded LDS row stride in ushorts for 32-wide k tiles (80B: 2-way bank alias = free)

static __device__ __forceinline__ u16 f2bf(float f){
  union { float f; uint32_t u; } a; a.f = f;
  return (u16)((a.u + 0x7fffu + ((a.u >> 16) & 1u)) >> 16);   // RNE, matches __float2bfloat16
}

// ---------------------------------------------------------------- token prep
// x = LayerNorm(mm); fusedb[b][0:1024] = bf16(x), fusedb[b][1024:2048] = bf16(query)
// also store mu/rstd so the fp64 router can rebuild x at fp32 precision.
__global__ __launch_bounds__(256) void k_token_prep(
    const float* __restrict__ mm, const float* __restrict__ qf,
    const float* __restrict__ gamma, const float* __restrict__ beta,
    u16* __restrict__ fusedb, float* __restrict__ mu, float* __restrict__ rstd)
{
  int b = blockIdx.x, t = threadIdx.x;
  __shared__ float red[16];
  float4 v = ((const float4*)(mm + (size_t)b*NH))[t];
  float s = v.x+v.y+v.z+v.w;
  for (int o=32;o;o>>=1) s += __shfl_down(s,o);
  int wid = t>>6, lane = t&63;
  if (!lane) red[wid] = s;
  __syncthreads();
  if (t==0) red[8] = (red[0]+red[1]+red[2]+red[3]) * (1.0f/NH);
  __syncthreads();
  float mean = red[8];
  float4 d; d.x=v.x-mean; d.y=v.y-mean; d.z=v.z-mean; d.w=v.w-mean;
  float s2 = d.x*d.x+d.y*d.y+d.z*d.z+d.w*d.w;
  for (int o=32;o;o>>=1) s2 += __shfl_down(s2,o);
  if (!lane) red[4+wid] = s2;
  __syncthreads();
  if (t==0) red[9] = rsqrtf((red[4]+red[5]+red[6]+red[7])*(1.0f/NH) + 1e-5f);
  __syncthreads();
  float rs = red[9];
  if (t==0){ mu[b]=mean; rstd[b]=rs; }
  float4 g = ((const float4*)gamma)[t], be = ((const float4*)beta)[t];
  ushort4 ox;
  ox.x = f2bf(d.x*rs*g.x+be.x); ox.y = f2bf(d.y*rs*g.y+be.y);
  ox.z = f2bf(d.z*rs*g.z+be.z); ox.w = f2bf(d.w*rs*g.w+be.w);
  ((ushort4*)(fusedb + (size_t)b*2048))[t] = ox;
  float4 q = ((const float4*)(qf + (size_t)b*NH))[t];
  ushort4 oq; oq.x=f2bf(q.x); oq.y=f2bf(q.y); oq.z=f2bf(q.z); oq.w=f2bf(q.w);
  ((ushort4*)(fusedb + (size_t)b*2048 + 1024))[t] = oq;
}

// ---------------------------------------------------------------- pilots l2norm (fp64 norm)
__global__ __launch_bounds__(256) void k_pilots(const float* __restrict__ pe, float* __restrict__ pn)
{
  int ec = blockIdx.x, t = threadIdx.x;
  __shared__ double dred[8];
  float4 v = ((const float4*)(pe + (size_t)ec*NH))[t];
  double s2 = (double)v.x*v.x + (double)v.y*v.y + (double)v.z*v.z + (double)v.w*v.w;
  for (int o=32;o;o>>=1) s2 += __shfl_down(s2,o);
  int wid=t>>6, lane=t&63;
  if (!lane) dred[wid]=s2;
  __syncthreads();
  if (t==0) dred[4] = 1.0 / fmax(sqrt(dred[0]+dred[1]+dred[2]+dred[3]), 1e-12);
  __syncthreads();
  double inv = dred[4];
  float4 o; o.x=(float)(v.x*inv); o.y=(float)(v.y*inv); o.z=(float)(v.z*inv); o.w=(float)(v.w*inv);
  ((float4*)(pn + (size_t)ec*NH))[t] = o;
}

// ---------------------------------------------------------------- M = qproj_W @ pn^T   [2048][32] fp64
__global__ __launch_bounds__(256) void k_M(const float* __restrict__ W, const float* __restrict__ pn,
                                           double* __restrict__ M)
{
  int j = blockIdx.x;                    // 0..2047
  __shared__ float wrow[NH];
  __shared__ double part[256];
  for (int i=threadIdx.x;i<NH;i+=256) wrow[i] = W[(size_t)j*NH + i];
  __syncthreads();
  int ec = threadIdx.x>>3, seg = threadIdx.x&7;
  const float* p = pn + (size_t)ec*NH + seg*128;
  const float* wr = wrow + seg*128;
  double a = 0;
  #pragma unroll 8
  for (int i=0;i<128;i++) a += (double)wr[i]*(double)p[i];
  part[threadIdx.x] = a;
  __syncthreads();
  if (seg==0){
    double s=0;
    for (int i=0;i<8;i++) s += part[(ec<<3)+i];
    M[(size_t)j*32 + ec] = s;
  }
}

// ---------------------------------------------------------------- small precomputes
// b1_all[9][1024]=eb1|sb1 ; cvec[9][64]=eb2@gW_top | sb2@gW_bot+gate_b ; cr[32]=qproj_b . pn
__global__ __launch_bounds__(256) void k_smalls(
    const float* eb1, const float* sb1, const float* eb2, const float* sb2,
    const float* gW, const float* gb, const float* qb, const float* pn,
    float* b1_all, float* cvec, double* cr)
{
  int idx = blockIdx.x*256 + threadIdx.x;
  if (idx < 9216){
    int e = idx>>10, k = idx&1023;
    b1_all[idx] = (e<8) ? eb1[idx] : sb1[k];
  } else if (idx < 9216+576){
    int i = idx-9216; int e = i>>6, n = i&63;
    float a = (e<8) ? 0.0f : gb[n];
    for (int j=0;j<64;j++){
      float bj = (e<8) ? eb2[e*64+j] : sb2[j];
      a += bj * gW[(((e<8)?j:64+j))*64 + n];
    }
    cvec[i] = a;
  } else if (idx < 9216+576+32){
    int ec = idx-9216-576;
    double a=0;
    for (int h=0;h<NH;h++) a += (double)qb[h]*(double)pn[(size_t)ec*NH+h];
    cr[ec] = a;
  }
}

// ---------------------------------------------------------------- generic f32->bf16 transpose: dst[n*K+k]=src[k*N+n]
__global__ __launch_bounds__(256) void k_transpose_bf16(const float* __restrict__ src, u16* __restrict__ dst,
                                                        int K, int N)
{
  __shared__ float tile[32][33];
  int k0 = blockIdx.x*32, n0 = blockIdx.y*32;
  int tx = threadIdx.x & 31, ty = threadIdx.x >> 5;
  for (int i=0;i<4;i++) tile[ty+i*8][tx] = src[(size_t)(k0+ty+i*8)*N + n0 + tx];
  __syncthreads();
  for (int i=0;i<4;i++) dst[(size_t)(n0+ty+i*8)*K + k0 + tx] = f2bf(tile[tx][ty+i*8]);
}

// W1-type transposes: slot e<8 from eW1[e], slot 8 from sW1 -> w1t[9][1024(n)][1024(k)] bf16
__global__ __launch_bounds__(256) void k_w1t(const float* __restrict__ eW1, const float* __restrict__ sW1,
                                             u16* __restrict__ w1t)
{
  __shared__ float tile[32][33];
  int e = blockIdx.z;
  const float* src = (e<8) ? eW1 + ((size_t)e<<20) : sW1;
  u16* dst = w1t + ((size_t)e<<20);
  int k0 = blockIdx.x*32, n0 = blockIdx.y*32;
  int tx = threadIdx.x & 31, ty = threadIdx.x >> 5;
  for (int i=0;i<4;i++) tile[ty+i*8][tx] = src[(size_t)(k0+ty+i*8)*NH + n0 + tx];
  __syncthreads();
  for (int i=0;i<4;i++) dst[(size_t)(n0+ty+i*8)*NH + k0 + tx] = f2bf(tile[tx][ty+i*8]);
}

// fold gate into W2: w2t[e][n][k] = bf16( sum_j W2src[k][j] * gW[rowbase+j][n] ), transposed [64(n)][1024(k)]
__global__ __launch_bounds__(256) void k_fold_w2(const float* __restrict__ eW2, const float* __restrict__ sW2,
                                                 const float* __restrict__ gW, u16* __restrict__ w2t)
{
  __shared__ float gsh[64*64];
  int e = blockIdx.y;
  const float* src = (e<8) ? eW2 + (size_t)e*NH*64 : sW2;
  int rowbase = (e<8) ? 0 : 64;
  for (int i=threadIdx.x;i<64*64;i+=256) gsh[i] = gW[(size_t)(rowbase + (i>>6))*64 + (i&63)];
  __syncthreads();
  int flat = blockIdx.x*256 + threadIdx.x;      // over n*1024 + k
  int n = flat >> 10, k = flat & 1023;
  float acc = 0;
  #pragma unroll 8
  for (int j=0;j<64;j++) acc += src[(size_t)k*64 + j] * gsh[j*64 + n];
  w2t[(size_t)e*64*NH + flat] = f2bf(acc);
}

// ---------------------------------------------------------------- fp64 router GEMM (ordering-critical)
// u[b][ec] += sum_k fused32[b][k] * M[k][ec]  over this block's K-chunk (splitK=8, 256 k each)
__global__ __launch_bounds__(256,1) void k_router(
    const float* __restrict__ mm, const float* __restrict__ qf,
    const float* __restrict__ gamma, const float* __restrict__ beta,
    const float* __restrict__ mu, const float* __restrict__ rstd,
    const double* __restrict__ M, double* __restrict__ u)
{
  __shared__ float At[16][521];     // [k][row], pad 521 (odd*~) -> conflict-light
  __shared__ double Ms[16][32];
  int rb = blockIdx.x * 512;
  int kc = blockIdx.y * 256;
  bool isx = (kc < 1024);
  const float* src = isx ? mm : qf;
  int ksrc = isx ? kc : kc-1024;
  int t = threadIdx.x;
  int kk4 = (t&3)*4, rr = t>>2;                  // staging: 4-k float4 x rows rr+64i
  int rg = t & 63, ec0 = (t>>6)*8;               // compute: rows rg+64i, ec ec0..ec0+7
  double acc[64];
  #pragma unroll
  for (int i=0;i<64;i++) acc[i]=0;

  for (int kb=0; kb<256; kb+=16){
    __syncthreads();
    float4 g4, b4;
    if (isx){ g4 = *(const float4*)(gamma + kc+kb+kk4); b4 = *(const float4*)(beta + kc+kb+kk4); }
    #pragma unroll
    for (int i=0;i<8;i++){
      int r = rr + i*64;
      float4 v = *(const float4*)(src + (size_t)(rb+r)*NH + ksrc + kb + kk4);
      if (isx){
        float m = mu[rb+r], rs = rstd[rb+r];
        v.x=(v.x-m)*rs*g4.x+b4.x; v.y=(v.y-m)*rs*g4.y+b4.y;
        v.z=(v.z-m)*rs*g4.z+b4.z; v.w=(v.w-m)*rs*g4.w+b4.w;
      }
      At[kk4+0][r]=v.x; At[kk4+1][r]=v.y; At[kk4+2][r]=v.z; At[kk4+3][r]=v.w;
    }
    const double* msrc = M + (size_t)(kc+kb)*32;
    ((double*)Ms)[t] = msrc[t];
    ((double*)Ms)[256+t] = msrc[256+t];
    __syncthreads();
    #pragma unroll
    for (int kk=0; kk<16; kk++){
      float a[8]; double m8[8];
      #pragma unroll
      for (int i=0;i<8;i++) a[i] = At[kk][rg + 64*i];
      #pragma unroll
      for (int j=0;j<8;j++) m8[j] = Ms[kk][ec0+j];
      #pragma unroll
      for (int i=0;i<8;i++)
        #pragma unroll
        for (int j=0;j<8;j++) acc[i*8+j] = fma((double)a[i], m8[j], acc[i*8+j]);
    }
  }
  #pragma unroll
  for (int i=0;i<8;i++){
    size_t row = (size_t)(rb + rg + 64*i);
    #pragma unroll
    for (int j=0;j<8;j++) unsafeAtomicAdd(&u[row*32 + ec0 + j], acc[i*8+j]);
  }
}

// ---------------------------------------------------------------- qproj norm GEMM (bf16 MFMA, norm only)
__global__ __launch_bounds__(256,2) void k_qnorm(
    const u16* __restrict__ fusedb, const u16* __restrict__ wqt,
    const float* __restrict__ qb, float* __restrict__ norm2)
{
  __shared__ u16 As[128*LDK];
  __shared__ u16 Bs[128*LDK];
  int nb = blockIdx.x*128, mb = blockIdx.y*128;
  int t = threadIdx.x;
  int arow0 = t>>2, c4 = (t&3)*8;
  const u16* ag0 = fusedb + (size_t)(mb+arow0)*2048 + c4;
  const u16* ag1 = fusedb + (size_t)(mb+arow0+64)*2048 + c4;
  const u16* bg0 = wqt + (size_t)(nb+arow0)*2048 + c4;
  const u16* bg1 = wqt + (size_t)(nb+arow0+64)*2048 + c4;
  u16* as0 = As + arow0*LDK + c4; u16* as1 = As + (arow0+64)*LDK + c4;
  u16* bs0 = Bs + arow0*LDK + c4; u16* bs1 = Bs + (arow0+64)*LDK + c4;
  int wid=t>>6, lane=t&63, quad=lane>>4, lr=lane&15;
  int wm=(wid&1)*64, wn=(wid>>1)*64;
  f32x4 acc[4][4] = {};
  for (int kb=0;kb<2048;kb+=32){
    __syncthreads();
    *(uint4*)as0 = *(const uint4*)(ag0+kb);
    *(uint4*)as1 = *(const uint4*)(ag1+kb);
    *(uint4*)bs0 = *(const uint4*)(bg0+kb);
    *(uint4*)bs1 = *(const uint4*)(bg1+kb);
    __syncthreads();
    short8 af[4], bf4[4];
    #pragma unroll
    for (int i=0;i<4;i++) af[i]  = *(const short8*)(As + (wm+i*16+lr)*LDK + quad*8);
    #pragma unroll
    for (int j=0;j<4;j++) bf4[j] = *(const short8*)(Bs + (wn+j*16+lr)*LDK + quad*8);
    #pragma unroll
    for (int i=0;i<4;i++)
      #pragma unroll
      for (int j=0;j<4;j++)
        acc[i][j] = __builtin_amdgcn_mfma_f32_16x16x32_bf16(af[i], bf4[j], acc[i][j], 0,0,0);
  }
  float rsum[4][4];
  #pragma unroll
  for (int i=0;i<4;i++)
    #pragma unroll
    for (int r=0;r<4;r++){
      float s=0;
      #pragma unroll
      for (int j=0;j<4;j++){
        int n = nb + wn + j*16 + lr;
        float v = acc[i][j][r] + qb[n];
        s += v*v;
      }
      rsum[i][r]=s;
    }
  #pragma unroll
  for (int m=1;m<16;m<<=1)
    #pragma unroll
    for (int i=0;i<4;i++)
      #pragma unroll
      for (int r=0;r<4;r++) rsum[i][r] += __shfl_xor(rsum[i][r], m);
  if (lr==0){
    #pragma unroll
    for (int i=0;i<4;i++)
      #pragma unroll
      for (int r=0;r<4;r++)
        unsafeAtomicAdd(&norm2[mb + wm + i*16 + quad*4 + r], rsum[i][r]);
  }
}

// ---------------------------------------------------------------- scores / softmax / top2 / counts
__global__ __launch_bounds__(256) void k_scores(
    const double* __restrict__ u, const double* __restrict__ cr, const float* __restrict__ norm2,
    int2* __restrict__ idx2, float2* __restrict__ w12, int* __restrict__ counts)
{
  __shared__ int lcnt[8];
  int t = threadIdx.x;
  if (t<8) lcnt[t]=0;
  __syncthreads();
  int b = blockIdx.x*256 + t;
  const double* ub = u + (size_t)b*32;
  double inv = 1.0 / fmax(sqrt((double)norm2[b]), 1e-12);
  double s[8];
  #pragma unroll
  for (int e=0;e<8;e++)
    s[e] = (ub[e*4]+cr[e*4] + ub[e*4+1]+cr[e*4+1] + ub[e*4+2]+cr[e*4+2] + ub[e*4+3]+cr[e*4+3]) * 0.25 * inv;
  int e1 = 0;
  for (int e=1;e<8;e++) if (s[e] > s[e1]) e1 = e;
  int e2 = (e1==0) ? 1 : 0;
  for (int e=0;e<8;e++) if (e!=e1 && s[e] > s[e2]) e2 = e;
  double mx = s[e1], S = 0, p[8];
  #pragma unroll
  for (int e=0;e<8;e++){ p[e] = exp((s[e]-mx)*10.0); S += p[e]; }   // /TEMP = *10
  double P1 = p[e1]/S, P2 = p[e2]/S;
  double den = P1 + P2 + 1e-6;
  idx2[b] = make_int2(e1,e2);
  w12[b]  = make_float2((float)(P1/den), (float)(P2/den));
  atomicAdd(&lcnt[e1],1); atomicAdd(&lcnt[e2],1);
  __syncthreads();
  if (t<8) atomicAdd(&counts[t], lcnt[t]);
}

__global__ void k_prefix(const int* counts, int* offs, int* cursor){
  if (threadIdx.x==0 && blockIdx.x==0){
    int o=0;
    for (int e=0;e<8;e++){ offs[e]=o; cursor[e]=o; o+=counts[e]; }
    offs[8]=o;   // == 2*NB
  }
}

__global__ __launch_bounds__(256) void k_fill(const int2* __restrict__ idx2, const float2* __restrict__ w12,
                                              int* cursor, int* __restrict__ tok_list, float* __restrict__ wt_list)
{
  __shared__ int lc[8], base[8];
  int t = threadIdx.x;
  if (t<8) lc[t]=0;
  __syncthreads();
  int b = blockIdx.x*256 + t;
  int2 e = idx2[b]; float2 w = w12[b];
  int p1 = atomicAdd(&lc[e.x],1);
  int p2 = atomicAdd(&lc[e.y],1);
  __syncthreads();
  if (t<8) base[t] = atomicAdd(&cursor[t], lc[t]);
  __syncthreads();
  int s1 = base[e.x]+p1, s2 = base[e.y]+p2;
  tok_list[s1]=b; wt_list[s1]=w.x;
  tok_list[s2]=b; wt_list[s2]=w.y;
  tok_list[2*NB + b] = b; wt_list[2*NB + b] = 1.0f;   // shared-expert identity slots
}

// ---------------------------------------------------------------- grouped GEMM1: h = relu(x @ W1[e] + b1[e])
__global__ __launch_bounds__(256,2) void k_gemm1(
    const u16* __restrict__ fusedb, const u16* __restrict__ w1t, const float* __restrict__ b1_all,
    const int* __restrict__ tok_list, const int* __restrict__ offs, const int* __restrict__ counts,
    u16* __restrict__ h)
{
  int e = blockIdx.z;
  int cnt = (e<8) ? counts[e] : NB;
  int off = (e<8) ? offs[e]   : 2*NB;
  int mb = blockIdx.y * 128;
  if (mb >= cnt) return;
  int rem = cnt - mb;
  int nb = blockIdx.x * 128;
  __shared__ u16 As[128*LDK];
  __shared__ u16 Bs[128*LDK];
  int t = threadIdx.x;
  int arow0 = t>>2, c4 = (t&3)*8;
  int r0c = arow0    < rem ? arow0    : rem-1;
  int r1c = arow0+64 < rem ? arow0+64 : rem-1;
  int tok0 = tok_list[off + mb + r0c];
  int tok1 = tok_list[off + mb + r1c];
  const u16* wbase = w1t + ((size_t)e<<20);
  const u16* ag0 = fusedb + (size_t)tok0*2048 + c4;     // x part: k in [0,1024)
  const u16* ag1 = fusedb + (size_t)tok1*2048 + c4;
  const u16* bg0 = wbase + (size_t)(nb+arow0)*NH + c4;
  const u16* bg1 = wbase + (size_t)(nb+arow0+64)*NH + c4;
  u16* as0 = As + arow0*LDK + c4; u16* as1 = As + (arow0+64)*LDK + c4;
  u16* bs0 = Bs + arow0*LDK + c4; u16* bs1 = Bs + (arow0+64)*LDK + c4;
  int wid=t>>6, lane=t&63, quad=lane>>4, lr=lane&15;
  int wm=(wid&1)*64, wn=(wid>>1)*64;
  f32x4 acc[4][4] = {};
  for (int kb=0;kb<1024;kb+=32){
    __syncthreads();
    *(uint4*)as0 = *(const uint4*)(ag0+kb);
    *(uint4*)as1 = *(const uint4*)(ag1+kb);
    *(uint4*)bs0 = *(const uint4*)(bg0+kb);
    *(uint4*)bs1 = *(const uint4*)(bg1+kb);
    __syncthreads();
    short8 af[4], bf4[4];
    #pragma unroll
    for (int i=0;i<4;i++) af[i]  = *(const short8*)(As + (wm+i*16+lr)*LDK + quad*8);
    #pragma unroll
    for (int j=0;j<4;j++) bf4[j] = *(const short8*)(Bs + (wn+j*16+lr)*LDK + quad*8);
    #pragma unroll
    for (int i=0;i<4;i++)
      #pragma unroll
      for (int j=0;j<4;j++)
        acc[i][j] = __builtin_amdgcn_mfma_f32_16x16x32_bf16(af[i], bf4[j], acc[i][j], 0,0,0);
  }
  const float* b1 = b1_all + e*NH;
  #pragma unroll
  for (int i=0;i<4;i++){
    #pragma unroll
    for (int reg=0; reg<4; reg++){
      int rr = wm + i*16 + quad*4 + reg;
      if (rr < rem){
        size_t hrow = (size_t)(off + mb + rr) * NH;
        #pragma unroll
        for (int j=0;j<4;j++){
          int n = nb + wn + j*16 + lr;
          float v = acc[i][j][reg] + b1[n];
          h[hrow + n] = f2bf(fmaxf(v, 0.0f));
        }
      }
    }
  }
}

// ---------------------------------------------------------------- grouped GEMM2: out_acc[tok] += wt * (h @ W2'[e])
__global__ __launch_bounds__(256,2) void k_gemm2(
    const u16* __restrict__ h, const u16* __restrict__ w2t,
    const int* __restrict__ tok_list, const float* __restrict__ wt_list,
    const int* __restrict__ offs, const int* __restrict__ counts,
    float* __restrict__ out_acc)
{
  int e = blockIdx.y;
  int cnt = (e<8) ? counts[e] : NB;
  int off = (e<8) ? offs[e]   : 2*NB;
  int mb = blockIdx.x * 128;
  if (mb >= cnt) return;
  int rem = cnt - mb;
  __shared__ u16 As[128*LDK];
  __shared__ u16 Bs[64*LDK];
  int t = threadIdx.x;
  int arow0 = t>>2, c4 = (t&3)*8;
  const u16* ah = h + (size_t)(off+mb)*NH;
  const u16* wb = w2t + (size_t)e*64*NH;
  int wid=t>>6, lane=t&63, quad=lane>>4, lr=lane&15;
  int wm = wid*32;
  f32x4 acc[2][4] = {};
  for (int kb=0;kb<1024;kb+=32){
    __syncthreads();
    *(uint4*)(As + arow0*LDK + c4)      = *(const uint4*)(ah + (size_t)arow0*NH + kb + c4);
    *(uint4*)(As + (arow0+64)*LDK + c4) = *(const uint4*)(ah + (size_t)(arow0+64)*NH + kb + c4);
    *(uint4*)(Bs + arow0*LDK + c4)      = *(const uint4*)(wb + (size_t)arow0*NH + kb + c4);
    __syncthreads();
    short8 af[2], bf4[4];
    #pragma unroll
    for (int i=0;i<2;i++) af[i]  = *(const short8*)(As + (wm+i*16+lr)*LDK + quad*8);
    #pragma unroll
    for (int j=0;j<4;j++) bf4[j] = *(const short8*)(Bs + (j*16+lr)*LDK + quad*8);
    #pragma unroll
    for (int i=0;i<2;i++)
      #pragma unroll
      for (int j=0;j<4;j++)
        acc[i][j] = __builtin_amdgcn_mfma_f32_16x16x32_bf16(af[i], bf4[j], acc[i][j], 0,0,0);
  }
  #pragma unroll
  for (int i=0;i<2;i++){
    #pragma unroll
    for (int reg=0; reg<4; reg++){
      int rr = wm + i*16 + quad*4 + reg;
      if (rr < rem){
        int slot = off + mb + rr;
        int tok = tok_list[slot];
        float w = wt_list[slot];
        float* dst = out_acc + (size_t)tok*64;
        #pragma unroll
        for (int j=0;j<4;j++)
          unsafeAtomicAdd(dst + j*16 + lr, w * acc[i][j][reg]);
      }
    }
  }
}

// ---------------------------------------------------------------- final: + folded biases, sigmoid
__global__ __launch_bounds__(256) void k_final(
    const float* __restrict__ out_acc, const float* __restrict__ cvec,
    const int2* __restrict__ idx2, const float2* __restrict__ w12, float* __restrict__ out)
{
  int i = blockIdx.x*256 + threadIdx.x;
  int b = i>>6, n = i&63;
  int2 e = idx2[b]; float2 w = w12[b];
  float v = out_acc[i] + w.x*cvec[e.x*64+n] + w.y*cvec[e.y*64+n] + cvec[8*64+n];
  out[i] = 1.0f / (1.0f + expf(-v));
}

// ================================================================ launch
extern "C" void kernel_launch(void* const* d_in, const int* in_sizes, int n_in,
                              void* d_out, int out_size, void* d_ws, size_t ws_size,
                              hipStream_t stream)
{
  (void)in_sizes; (void)n_in; (void)out_size; (void)ws_size;
  const float* mm   =(const float*)d_in[0];
  const float* qf   =(const float*)d_in[1];
  const float* gamma=(const float*)d_in[2];
  const float* beta =(const float*)d_in[3];
  const float* pe   =(const float*)d_in[4];
  const float* qW   =(const float*)d_in[5];
  const float* qb   =(const float*)d_in[6];
  const float* eW1  =(const float*)d_in[7];
  const float* eb1  =(const float*)d_in[8];
  const float* eW2  =(const float*)d_in[9];
  const float* eb2  =(const float*)d_in[10];
  const float* sW1  =(const float*)d_in[11];
  const float* sb1  =(const float*)d_in[12];
  const float* sW2  =(const float*)d_in[13];
  const float* sb2  =(const float*)d_in[14];
  const float* gW   =(const float*)d_in[15];
  const float* gb   =(const float*)d_in[16];
  float* out = (float*)d_out;

  char* p = (char*)d_ws;
  auto alloc = [&](size_t bytes)->char*{ char* r = p; p += (bytes + 255) & ~(size_t)255; return r; };
  // zero-init region (one memset)
  double* u       = (double*)alloc((size_t)NB*32*8);
  float*  out_acc = (float*) alloc((size_t)NB*64*4);
  float*  norm2   = (float*) alloc((size_t)NB*4);
  int*    counts  = (int*)   alloc(64);
  int*    cursor  = (int*)   alloc(64);
  int*    offs    = (int*)   alloc(64);
  size_t zero_bytes = (size_t)(p - (char*)d_ws);
  // rest
  u16*    fusedb  = (u16*)   alloc((size_t)NB*2048*2);
  u16*    h       = (u16*)   alloc((size_t)NSLOT*NH*2);
  u16*    w1t     = (u16*)   alloc((size_t)9*NH*NH*2);
  u16*    wqt     = (u16*)   alloc((size_t)NH*2048*2);
  u16*    w2t     = (u16*)   alloc((size_t)9*64*NH*2);
  float*  b1_all  = (float*) alloc((size_t)9*NH*4);
  float*  cvec    = (float*) alloc((size_t)9*64*4);
  double* M       = (double*)alloc((size_t)2048*32*8);
  float*  pn      = (float*) alloc((size_t)32*NH*4);
  double* cr      = (double*)alloc(32*8);
  float*  mu      = (float*) alloc((size_t)NB*4);
  float*  rstd    = (float*) alloc((size_t)NB*4);
  int2*   idx2    = (int2*)  alloc((size_t)NB*8);
  float2* w12     = (float2*)alloc((size_t)NB*8);
  int*    tok_list= (int*)   alloc((size_t)NSLOT*4);
  float*  wt_list = (float*) alloc((size_t)NSLOT*4);

  hipMemsetAsync(d_ws, 0, zero_bytes, stream);
  k_token_prep<<<NB, 256, 0, stream>>>(mm, qf, gamma, beta, fusedb, mu, rstd);
  k_pilots<<<32, 256, 0, stream>>>(pe, pn);
  k_M<<<2048, 256, 0, stream>>>(qW, pn, M);
  k_smalls<<<39, 256, 0, stream>>>(eb1, sb1, eb2, sb2, gW, gb, qb, pn, b1_all, cvec, cr);
  k_transpose_bf16<<<dim3(64,32), 256, 0, stream>>>(qW, wqt, 2048, 1024);
  k_w1t<<<dim3(32,32,9), 256, 0, stream>>>(eW1, sW1, w1t);
  k_fold_w2<<<dim3(256,9), 256, 0, stream>>>(eW2, sW2, gW, w2t);
  k_qnorm<<<dim3(8,128), 256, 0, stream>>>(fusedb, wqt, qb, norm2);
  k_router<<<dim3(32,8), 256, 0, stream>>>(mm, qf, gamma, beta, mu, rstd, M, u);
  k_scores<<<64, 256, 0, stream>>>(u, cr, norm2, idx2, w12, counts);
  k_prefix<<<1, 64, 0, stream>>>(counts, offs, cursor);
  k_fill<<<64, 256, 0, stream>>>(idx2, w12, cursor, tok_list, wt_list);
  k_gemm1<<<dim3(8,128,9), 256, 0, stream>>>(fusedb, w1t, b1_all, tok_list, offs, counts, h);
  k_gemm2<<<dim3(128,9), 256, 0, stream>>>(h, w2t, tok_list, wt_list, offs, counts, out_acc);
  k_final<<<4096, 256, 0, stream>>>(out_acc, cvec, idx2, w12, out);
}

// Round 2
// 703.541 us; speedup vs baseline: 1.2466x; 1.2466x over previous
//
#include <hip/hip_runtime.h>
#include <hip/hip_bf16.h>
#include <stdint.h>

typedef unsigned short u16;
typedef __attribute__((ext_vector_type(8))) short short8;
typedef __attribute__((ext_vector_type(4))) float f32x4;

#define NB 16384      // batch
#define NH 1024       // hidden
#define NSLOT 49152   // 2*NB routed slots + NB shared ("expert 8") slots
#define NCHUNK 4      // router split-K chunks (512 k each)

static __device__ __forceinline__ u16 f2bf(float f){
  union { float f; uint32_t u; } a; a.f = f;
  return (u16)((a.u + 0x7fffu + ((a.u >> 16) & 1u)) >> 16);   // RNE, matches __float2bfloat16
}

// async global->LDS, 16B per lane. LDS dest must be wave-uniform base + lane*16.
static __device__ __forceinline__ void gld16(const u16* gsrc, u16* lds){
  __builtin_amdgcn_global_load_lds((const __attribute__((address_space(1))) void*)gsrc,
                                   (__attribute__((address_space(3))) void*)lds, 16, 0, 0);
}

// ---------------------------------------------------------------- token prep
__global__ __launch_bounds__(256) void k_token_prep(
    const float* __restrict__ mm, const float* __restrict__ qf,
    const float* __restrict__ gamma, const float* __restrict__ beta,
    u16* __restrict__ fusedb, float* __restrict__ mu, float* __restrict__ rstd)
{
  int b = blockIdx.x, t = threadIdx.x;
  __shared__ float red[16];
  float4 v = ((const float4*)(mm + (size_t)b*NH))[t];
  float s = v.x+v.y+v.z+v.w;
  for (int o=32;o;o>>=1) s += __shfl_down(s,o);
  int wid = t>>6, lane = t&63;
  if (!lane) red[wid] = s;
  __syncthreads();
  if (t==0) red[8] = (red[0]+red[1]+red[2]+red[3]) * (1.0f/NH);
  __syncthreads();
  float mean = red[8];
  float4 d; d.x=v.x-mean; d.y=v.y-mean; d.z=v.z-mean; d.w=v.w-mean;
  float s2 = d.x*d.x+d.y*d.y+d.z*d.z+d.w*d.w;
  for (int o=32;o;o>>=1) s2 += __shfl_down(s2,o);
  if (!lane) red[4+wid] = s2;
  __syncthreads();
  if (t==0) red[9] = rsqrtf((red[4]+red[5]+red[6]+red[7])*(1.0f/NH) + 1e-5f);
  __syncthreads();
  float rs = red[9];
  if (t==0){ mu[b]=mean; rstd[b]=rs; }
  float4 g = ((const float4*)gamma)[t], be = ((const float4*)beta)[t];
  ushort4 ox;
  ox.x = f2bf(d.x*rs*g.x+be.x); ox.y = f2bf(d.y*rs*g.y+be.y);
  ox.z = f2bf(d.z*rs*g.z+be.z); ox.w = f2bf(d.w*rs*g.w+be.w);
  ((ushort4*)(fusedb + (size_t)b*2048))[t] = ox;
  float4 q = ((const float4*)(qf + (size_t)b*NH))[t];
  ushort4 oq; oq.x=f2bf(q.x); oq.y=f2bf(q.y); oq.z=f2bf(q.z); oq.w=f2bf(q.w);
  ((ushort4*)(fusedb + (size_t)b*2048 + 1024))[t] = oq;
}

// ---------------------------------------------------------------- pilots l2norm (fp64 norm)
__global__ __launch_bounds__(256) void k_pilots(const float* __restrict__ pe, float* __restrict__ pn)
{
  int ec = blockIdx.x, t = threadIdx.x;
  __shared__ double dred[8];
  float4 v = ((const float4*)(pe + (size_t)ec*NH))[t];
  double s2 = (double)v.x*v.x + (double)v.y*v.y + (double)v.z*v.z + (double)v.w*v.w;
  for (int o=32;o;o>>=1) s2 += __shfl_down(s2,o);
  int wid=t>>6, lane=t&63;
  if (!lane) dred[wid]=s2;
  __syncthreads();
  if (t==0) dred[4] = 1.0 / fmax(sqrt(dred[0]+dred[1]+dred[2]+dred[3]), 1e-12);
  __syncthreads();
  double inv = dred[4];
  float4 o; o.x=(float)(v.x*inv); o.y=(float)(v.y*inv); o.z=(float)(v.z*inv); o.w=(float)(v.w*inv);
  ((float4*)(pn + (size_t)ec*NH))[t] = o;
}

// ---------------------------------------------------------------- M = qproj_W @ pn^T   [2048][32] fp64
__global__ __launch_bounds__(256) void k_M(const float* __restrict__ W, const float* __restrict__ pn,
                                           double* __restrict__ M)
{
  int j = blockIdx.x;                    // 0..2047
  __shared__ float wrow[NH];
  __shared__ double part[256];
  for (int i=threadIdx.x;i<NH;i+=256) wrow[i] = W[(size_t)j*NH + i];
  __syncthreads();
  int ec = threadIdx.x>>3, seg = threadIdx.x&7;
  const float* p = pn + (size_t)ec*NH + seg*128;
  const float* wr = wrow + seg*128;
  double a = 0;
  #pragma unroll 8
  for (int i=0;i<128;i++) a += (double)wr[i]*(double)p[i];
  part[threadIdx.x] = a;
  __syncthreads();
  if (seg==0){
    double s=0;
    for (int i=0;i<8;i++) s += part[(ec<<3)+i];
    M[(size_t)j*32 + ec] = s;
  }
}

// ---------------------------------------------------------------- small precomputes
__global__ __launch_bounds__(256) void k_smalls(
    const float* eb1, const float* sb1, const float* eb2, const float* sb2,
    const float* gW, const float* gb, const float* qb, const float* pn,
    float* b1_all, float* cvec, double* cr)
{
  int idx = blockIdx.x*256 + threadIdx.x;
  if (idx < 9216){
    int e = idx>>10, k = idx&1023;
    b1_all[idx] = (e<8) ? eb1[idx] : sb1[k];
  } else if (idx < 9216+576){
    int i = idx-9216; int e = i>>6, n = i&63;
    float a = (e<8) ? 0.0f : gb[n];
    for (int j=0;j<64;j++){
      float bj = (e<8) ? eb2[e*64+j] : sb2[j];
      a += bj * gW[(((e<8)?j:64+j))*64 + n];
    }
    cvec[i] = a;
  } else if (idx < 9216+576+32){
    int ec = idx-9216-576;
    double a=0;
    for (int h=0;h<NH;h++) a += (double)qb[h]*(double)pn[(size_t)ec*NH+h];
    cr[ec] = a;
  }
}

// ---------------------------------------------------------------- f32->bf16 transpose: dst[n*K+k]=src[k*N+n]
__global__ __launch_bounds__(256) void k_transpose_bf16(const float* __restrict__ src, u16* __restrict__ dst,
                                                        int K, int N)
{
  __shared__ float tile[32][33];
  int k0 = blockIdx.x*32, n0 = blockIdx.y*32;
  int tx = threadIdx.x & 31, ty = threadIdx.x >> 5;
  for (int i=0;i<4;i++) tile[ty+i*8][tx] = src[(size_t)(k0+ty+i*8)*N + n0 + tx];
  __syncthreads();
  for (int i=0;i<4;i++) dst[(size_t)(n0+ty+i*8)*K + k0 + tx] = f2bf(tile[tx][ty+i*8]);
}

__global__ __launch_bounds__(256) void k_w1t(const float* __restrict__ eW1, const float* __restrict__ sW1,
                                             u16* __restrict__ w1t)
{
  __shared__ float tile[32][33];
  int e = blockIdx.z;
  const float* src = (e<8) ? eW1 + ((size_t)e<<20) : sW1;
  u16* dst = w1t + ((size_t)e<<20);
  int k0 = blockIdx.x*32, n0 = blockIdx.y*32;
  int tx = threadIdx.x & 31, ty = threadIdx.x >> 5;
  for (int i=0;i<4;i++) tile[ty+i*8][tx] = src[(size_t)(k0+ty+i*8)*NH + n0 + tx];
  __syncthreads();
  for (int i=0;i<4;i++) dst[(size_t)(n0+ty+i*8)*NH + k0 + tx] = f2bf(tile[tx][ty+i*8]);
}

__global__ __launch_bounds__(256) void k_fold_w2(const float* __restrict__ eW2, const float* __restrict__ sW2,
                                                 const float* __restrict__ gW, u16* __restrict__ w2t)
{
  __shared__ float gsh[64*64];
  int e = blockIdx.y;
  const float* src = (e<8) ? eW2 + (size_t)e*NH*64 : sW2;
  int rowbase = (e<8) ? 0 : 64;
  for (int i=threadIdx.x;i<64*64;i+=256) gsh[i] = gW[(size_t)(rowbase + (i>>6))*64 + (i&63)];
  __syncthreads();
  int flat = blockIdx.x*256 + threadIdx.x;      // over n*1024 + k
  int n = flat >> 10, k = flat & 1023;
  float acc = 0;
  #pragma unroll 8
  for (int j=0;j<64;j++) acc += src[(size_t)k*64 + j] * gsh[j*64 + n];
  w2t[(size_t)e*64*NH + flat] = f2bf(acc);
}

// ---------------------------------------------------------------- fp64 router GEMM (ordering-critical)
// u_part[chunk][b][ec] = sum_{k in chunk} fused32[b][k] * M[k][ec]; 128-row x 512-k blocks.
// 16 fp64 acc/thread (4 rows x 4 ec); deterministic partials, no atomics.
__global__ __launch_bounds__(256) void k_router(
    const float* __restrict__ mm, const float* __restrict__ qf,
    const float* __restrict__ gamma, const float* __restrict__ beta,
    const float* __restrict__ mu, const float* __restrict__ rstd,
    const double* __restrict__ M, double* __restrict__ u_part)
{
  __shared__ float At[16][130];     // [k][row], stride 130: consecutive rows shift 2 banks
  __shared__ double Ms[16][32];
  int rb = blockIdx.x * 128;
  int kc = blockIdx.y * 512;
  bool isx = (kc < 1024);
  const float* src = isx ? mm : qf;
  int ksrc = isx ? kc : kc-1024;
  int t = threadIdx.x;
  int kk4 = (t&3)*4, rr = t>>2;                  // staging: 4-k float4, rows rr / rr+64
  int rg4 = t & 31, ec0 = (t>>5)*4;              // compute: rows rg4+32i, ec ec0..ec0+3
  double acc[4][4] = {};

  for (int kb=0; kb<512; kb+=16){
    __syncthreads();
    float4 g4, b4;
    if (isx){ g4 = *(const float4*)(gamma + kc+kb+kk4); b4 = *(const float4*)(beta + kc+kb+kk4); }
    #pragma unroll
    for (int i=0;i<2;i++){
      int r = rr + i*64;
      float4 v = *(const float4*)(src + (size_t)(rb+r)*NH + ksrc + kb + kk4);
      if (isx){
        float m = mu[rb+r], rs = rstd[rb+r];
        v.x=(v.x-m)*rs*g4.x+b4.x; v.y=(v.y-m)*rs*g4.y+b4.y;
        v.z=(v.z-m)*rs*g4.z+b4.z; v.w=(v.w-m)*rs*g4.w+b4.w;
      }
      At[kk4+0][r]=v.x; At[kk4+1][r]=v.y; At[kk4+2][r]=v.z; At[kk4+3][r]=v.w;
    }
    const double* msrc = M + (size_t)(kc+kb)*32;
    ((double*)Ms)[t]     = msrc[t];
    ((double*)Ms)[256+t] = msrc[256+t];
    __syncthreads();
    #pragma unroll
    for (int kk=0; kk<16; kk++){
      float a4[4]; double m4[4];
      #pragma unroll
      for (int i=0;i<4;i++) a4[i] = At[kk][rg4 + 32*i];      // conflict-free, half-wave broadcast
      #pragma unroll
      for (int j=0;j<4;j++) m4[j] = Ms[kk][ec0+j];            // 32-lane broadcast
      #pragma unroll
      for (int i=0;i<4;i++)
        #pragma unroll
        for (int j=0;j<4;j++) acc[i][j] = fma((double)a4[i], m4[j], acc[i][j]);
    }
  }
  double* dst = u_part + ((size_t)blockIdx.y*NB + rb)*32;
  #pragma unroll
  for (int i=0;i<4;i++){
    size_t row = (size_t)(rg4 + 32*i);
    #pragma unroll
    for (int j=0;j<4;j++) dst[row*32 + ec0 + j] = acc[i][j];
  }
}

// ---------------------------------------------------------------- qproj norm GEMM (bf16 MFMA, async staging)
__global__ __launch_bounds__(256,2) void k_qnorm(
    const u16* __restrict__ fusedb, const u16* __restrict__ wqt,
    const float* __restrict__ qb, float* __restrict__ norm2)
{
  __shared__ u16 As[128*32];
  __shared__ u16 Bs[128*32];
  int nb = blockIdx.x*128, mb = blockIdx.y*128;
  int t = threadIdx.x;
  int r0 = t>>2, c16 = (t&3)*8;
  const u16* ag0 = fusedb + (size_t)(mb+r0)*2048 + c16;
  const u16* ag1 = fusedb + (size_t)(mb+r0+64)*2048 + c16;
  const u16* bg0 = wqt + (size_t)(nb+r0)*2048 + c16;
  const u16* bg1 = wqt + (size_t)(nb+r0+64)*2048 + c16;
  u16* la0 = As + t*8;  u16* la1 = As + 2048 + t*8;
  u16* lb0 = Bs + t*8;  u16* lb1 = Bs + 2048 + t*8;
  int wid=t>>6, lane=t&63, quad=lane>>4, lr=lane&15;
  int wm=(wid&1)*64, wn=(wid>>1)*64;
  f32x4 acc[4][4] = {};
  for (int kb=0;kb<2048;kb+=32){
    __syncthreads();
    gld16(ag0+kb, la0); gld16(ag1+kb, la1);
    gld16(bg0+kb, lb0); gld16(bg1+kb, lb1);
    __syncthreads();
    short8 af[4], bf4[4];
    #pragma unroll
    for (int i=0;i<4;i++) af[i]  = *(const short8*)(As + (wm+i*16+lr)*32 + quad*8);
    #pragma unroll
    for (int j=0;j<4;j++) bf4[j] = *(const short8*)(Bs + (wn+j*16+lr)*32 + quad*8);
    #pragma unroll
    for (int i=0;i<4;i++)
      #pragma unroll
      for (int j=0;j<4;j++)
        acc[i][j] = __builtin_amdgcn_mfma_f32_16x16x32_bf16(af[i], bf4[j], acc[i][j], 0,0,0);
  }
  float rsum[4][4];
  #pragma unroll
  for (int i=0;i<4;i++)
    #pragma unroll
    for (int r=0;r<4;r++){
      float s=0;
      #pragma unroll
      for (int j=0;j<4;j++){
        int n = nb + wn + j*16 + lr;
        float v = acc[i][j][r] + qb[n];
        s += v*v;
      }
      rsum[i][r]=s;
    }
  #pragma unroll
  for (int m=1;m<16;m<<=1)
    #pragma unroll
    for (int i=0;i<4;i++)
      #pragma unroll
      for (int r=0;r<4;r++) rsum[i][r] += __shfl_xor(rsum[i][r], m);
  if (lr==0){
    #pragma unroll
    for (int i=0;i<4;i++)
      #pragma unroll
      for (int r=0;r<4;r++)
        unsafeAtomicAdd(&norm2[mb + wm + i*16 + quad*4 + r], rsum[i][r]);
  }
}

// ---------------------------------------------------------------- scores / softmax / top2 / counts
__global__ __launch_bounds__(256) void k_scores(
    const double* __restrict__ u_part, const double* __restrict__ cr, const float* __restrict__ norm2,
    int2* __restrict__ idx2, float2* __restrict__ w12, int* __restrict__ counts)
{
  __shared__ int lcnt[8];
  int t = threadIdx.x;
  if (t<8) lcnt[t]=0;
  __syncthreads();
  int b = blockIdx.x*256 + t;
  double s[8];
  #pragma unroll
  for (int e=0;e<8;e++) s[e] = cr[e*4]+cr[e*4+1]+cr[e*4+2]+cr[e*4+3];
  for (int c=0;c<NCHUNK;c++){
    const double* up = u_part + ((size_t)c*NB + b)*32;
    #pragma unroll
    for (int e=0;e<8;e++) s[e] += up[e*4]+up[e*4+1]+up[e*4+2]+up[e*4+3];
  }
  double inv = 0.25 / fmax(sqrt((double)norm2[b]), 1e-12);
  #pragma unroll
  for (int e=0;e<8;e++) s[e] *= inv;
  int e1 = 0;
  for (int e=1;e<8;e++) if (s[e] > s[e1]) e1 = e;
  int e2 = (e1==0) ? 1 : 0;
  for (int e=0;e<8;e++) if (e!=e1 && s[e] > s[e2]) e2 = e;
  double mx = s[e1], S = 0, p[8];
  #pragma unroll
  for (int e=0;e<8;e++){ p[e] = exp((s[e]-mx)*10.0); S += p[e]; }   // /TEMP = *10
  double P1 = p[e1]/S, P2 = p[e2]/S;
  double den = P1 + P2 + 1e-6;
  idx2[b] = make_int2(e1,e2);
  w12[b]  = make_float2((float)(P1/den), (float)(P2/den));
  atomicAdd(&lcnt[e1],1); atomicAdd(&lcnt[e2],1);
  __syncthreads();
  if (t<8) atomicAdd(&counts[t], lcnt[t]);
}

__global__ void k_prefix(const int* counts, int* offs, int* cursor){
  if (threadIdx.x==0 && blockIdx.x==0){
    int o=0;
    for (int e=0;e<8;e++){ offs[e]=o; cursor[e]=o; o+=counts[e]; }
    offs[8]=o;   // == 2*NB
  }
}

__global__ __launch_bounds__(256) void k_fill(const int2* __restrict__ idx2, const float2* __restrict__ w12,
                                              int* cursor, int* __restrict__ tok_list, float* __restrict__ wt_list)
{
  __shared__ int lc[8], base[8];
  int t = threadIdx.x;
  if (t<8) lc[t]=0;
  __syncthreads();
  int b = blockIdx.x*256 + t;
  int2 e = idx2[b]; float2 w = w12[b];
  int p1 = atomicAdd(&lc[e.x],1);
  int p2 = atomicAdd(&lc[e.y],1);
  __syncthreads();
  if (t<8) base[t] = atomicAdd(&cursor[t], lc[t]);
  __syncthreads();
  int s1 = base[e.x]+p1, s2 = base[e.y]+p2;
  tok_list[s1]=b; wt_list[s1]=w.x;
  tok_list[s2]=b; wt_list[s2]=w.y;
  tok_list[2*NB + b] = b; wt_list[2*NB + b] = 1.0f;   // shared-expert identity slots
}

// ---------------------------------------------------------------- grouped GEMM1: h = relu(x @ W1[e] + b1[e])
__global__ __launch_bounds__(256,2) void k_gemm1(
    const u16* __restrict__ fusedb, const u16* __restrict__ w1t, const float* __restrict__ b1_all,
    const int* __restrict__ tok_list, const int* __restrict__ offs, const int* __restrict__ counts,
    u16* __restrict__ h)
{
  int e = blockIdx.z;
  int cnt = (e<8) ? counts[e] : NB;
  int off = (e<8) ? offs[e]   : 2*NB;
  int mb = blockIdx.y * 128;
  if (mb >= cnt) return;
  int rem = cnt - mb;
  int nb = blockIdx.x * 128;
  __shared__ u16 As[128*32];
  __shared__ u16 Bs[128*32];
  int t = threadIdx.x;
  int r0 = t>>2, c16 = (t&3)*8;
  int r0c = r0    < rem ? r0    : rem-1;
  int r1c = r0+64 < rem ? r0+64 : rem-1;
  int tok0 = tok_list[off + mb + r0c];
  int tok1 = tok_list[off + mb + r1c];
  const u16* wbase = w1t + ((size_t)e<<20);
  const u16* ag0 = fusedb + (size_t)tok0*2048 + c16;     // x part: k in [0,1024)
  const u16* ag1 = fusedb + (size_t)tok1*2048 + c16;
  const u16* bg0 = wbase + (size_t)(nb+r0)*NH + c16;
  const u16* bg1 = wbase + (size_t)(nb+r0+64)*NH + c16;
  u16* la0 = As + t*8;  u16* la1 = As + 2048 + t*8;
  u16* lb0 = Bs + t*8;  u16* lb1 = Bs + 2048 + t*8;
  int wid=t>>6, lane=t&63, quad=lane>>4, lr=lane&15;
  int wm=(wid&1)*64, wn=(wid>>1)*64;
  f32x4 acc[4][4] = {};
  for (int kb=0;kb<1024;kb+=32){
    __syncthreads();
    gld16(ag0+kb, la0); gld16(ag1+kb, la1);
    gld16(bg0+kb, lb0); gld16(bg1+kb, lb1);
    __syncthreads();
    short8 af[4], bf4[4];
    #pragma unroll
    for (int i=0;i<4;i++) af[i]  = *(const short8*)(As + (wm+i*16+lr)*32 + quad*8);
    #pragma unroll
    for (int j=0;j<4;j++) bf4[j] = *(const short8*)(Bs + (wn+j*16+lr)*32 + quad*8);
    #pragma unroll
    for (int i=0;i<4;i++)
      #pragma unroll
      for (int j=0;j<4;j++)
        acc[i][j] = __builtin_amdgcn_mfma_f32_16x16x32_bf16(af[i], bf4[j], acc[i][j], 0,0,0);
  }
  const float* b1 = b1_all + e*NH;
  #pragma unroll
  for (int i=0;i<4;i++){
    #pragma unroll
    for (int reg=0; reg<4; reg++){
      int rr = wm + i*16 + quad*4 + reg;
      if (rr < rem){
        size_t hrow = (size_t)(off + mb + rr) * NH;
        #pragma unroll
        for (int j=0;j<4;j++){
          int n = nb + wn + j*16 + lr;
          float v = acc[i][j][reg] + b1[n];
          h[hrow + n] = f2bf(fmaxf(v, 0.0f));
        }
      }
    }
  }
}

// ---------------------------------------------------------------- grouped GEMM2: out_acc[tok] += wt * (h @ W2'[e])
__global__ __launch_bounds__(256,2) void k_gemm2(
    const u16* __restrict__ h, const u16* __restrict__ w2t,
    const int* __restrict__ tok_list, const float* __restrict__ wt_list,
    const int* __restrict__ offs, const int* __restrict__ counts,
    float* __restrict__ out_acc)
{
  int e = blockIdx.y;
  int cnt = (e<8) ? counts[e] : NB;
  int off = (e<8) ? offs[e]   : 2*NB;
  int mb = blockIdx.x * 128;
  if (mb >= cnt) return;
  int rem = cnt - mb;
  __shared__ u16 As[128*32];
  __shared__ u16 Bs[64*32];
  int t = threadIdx.x;
  int r0 = t>>2, c16 = (t&3)*8;
  const u16* ah = h + (size_t)(off+mb)*NH;
  const u16* ag0 = ah + (size_t)r0*NH + c16;
  const u16* ag1 = ah + (size_t)(r0+64)*NH + c16;
  const u16* bg0 = w2t + (size_t)e*64*NH + (size_t)r0*NH + c16;
  u16* la0 = As + t*8;  u16* la1 = As + 2048 + t*8;
  u16* lb0 = Bs + t*8;
  int wid=t>>6, lane=t&63, quad=lane>>4, lr=lane&15;
  int wm = wid*32;
  f32x4 acc[2][4] = {};
  for (int kb=0;kb<1024;kb+=32){
    __syncthreads();
    gld16(ag0+kb, la0); gld16(ag1+kb, la1);
    gld16(bg0+kb, lb0);
    __syncthreads();
    short8 af[2], bf4[4];
    #pragma unroll
    for (int i=0;i<2;i++) af[i]  = *(const short8*)(As + (wm+i*16+lr)*32 + quad*8);
    #pragma unroll
    for (int j=0;j<4;j++) bf4[j] = *(const short8*)(Bs + (j*16+lr)*32 + quad*8);
    #pragma unroll
    for (int i=0;i<2;i++)
      #pragma unroll
      for (int j=0;j<4;j++)
        acc[i][j] = __builtin_amdgcn_mfma_f32_16x16x32_bf16(af[i], bf4[j], acc[i][j], 0,0,0);
  }
  #pragma unroll
  for (int i=0;i<2;i++){
    #pragma unroll
    for (int reg=0; reg<4; reg++){
      int rr = wm + i*16 + quad*4 + reg;
      if (rr < rem){
        int slot = off + mb + rr;
        int tok = tok_list[slot];
        float w = wt_list[slot];
        float* dst = out_acc + (size_t)tok*64;
        #pragma unroll
        for (int j=0;j<4;j++)
          unsafeAtomicAdd(dst + j*16 + lr, w * acc[i][j][reg]);
      }
    }
  }
}

// ---------------------------------------------------------------- final: + folded biases, sigmoid
__global__ __launch_bounds__(256) void k_final(
    const float* __restrict__ out_acc, const float* __restrict__ cvec,
    const int2* __restrict__ idx2, const float2* __restrict__ w12, float* __restrict__ out)
{
  int i = blockIdx.x*256 + threadIdx.x;
  int b = i>>6, n = i&63;
  int2 e = idx2[b]; float2 w = w12[b];
  float v = out_acc[i] + w.x*cvec[e.x*64+n] + w.y*cvec[e.y*64+n] + cvec[8*64+n];
  out[i] = 1.0f / (1.0f + expf(-v));
}

// ================================================================ launch
extern "C" void kernel_launch(void* const* d_in, const int* in_sizes, int n_in,
                              void* d_out, int out_size, void* d_ws, size_t ws_size,
                              hipStream_t stream)
{
  (void)in_sizes; (void)n_in; (void)out_size; (void)ws_size;
  const float* mm   =(const float*)d_in[0];
  const float* qf   =(const float*)d_in[1];
  const float* gamma=(const float*)d_in[2];
  const float* beta =(const float*)d_in[3];
  const float* pe   =(const float*)d_in[4];
  const float* qW   =(const float*)d_in[5];
  const float* qb   =(const float*)d_in[6];
  const float* eW1  =(const float*)d_in[7];
  const float* eb1  =(const float*)d_in[8];
  const float* eW2  =(const float*)d_in[9];
  const float* eb2  =(const float*)d_in[10];
  const float* sW1  =(const float*)d_in[11];
  const float* sb1  =(const float*)d_in[12];
  const float* sW2  =(const float*)d_in[13];
  const float* sb2  =(const float*)d_in[14];
  const float* gW   =(const float*)d_in[15];
  const float* gb   =(const float*)d_in[16];
  float* out = (float*)d_out;

  char* p = (char*)d_ws;
  auto alloc = [&](size_t bytes)->char*{ char* r = p; p += (bytes + 255) & ~(size_t)255; return r; };
  // zero-init region (one memset)
  float*  out_acc = (float*) alloc((size_t)NB*64*4);
  float*  norm2   = (float*) alloc((size_t)NB*4);
  int*    counts  = (int*)   alloc(64);
  int*    cursor  = (int*)   alloc(64);
  int*    offs    = (int*)   alloc(64);
  size_t zero_bytes = (size_t)(p - (char*)d_ws);
  // rest (fully overwritten every call)
  double* u_part  = (double*)alloc((size_t)NCHUNK*NB*32*8);
  u16*    fusedb  = (u16*)   alloc((size_t)NB*2048*2);
  u16*    h       = (u16*)   alloc((size_t)NSLOT*NH*2);
  u16*    w1t     = (u16*)   alloc((size_t)9*NH*NH*2);
  u16*    wqt     = (u16*)   alloc((size_t)NH*2048*2);
  u16*    w2t     = (u16*)   alloc((size_t)9*64*NH*2);
  float*  b1_all  = (float*) alloc((size_t)9*NH*4);
  float*  cvec    = (float*) alloc((size_t)9*64*4);
  double* M       = (double*)alloc((size_t)2048*32*8);
  float*  pn      = (float*) alloc((size_t)32*NH*4);
  double* cr      = (double*)alloc(32*8);
  float*  mu      = (float*) alloc((size_t)NB*4);
  float*  rstd    = (float*) alloc((size_t)NB*4);
  int2*   idx2    = (int2*)  alloc((size_t)NB*8);
  float2* w12     = (float2*)alloc((size_t)NB*8);
  int*    tok_list= (int*)   alloc((size_t)NSLOT*4);
  float*  wt_list = (float*) alloc((size_t)NSLOT*4);

  hipMemsetAsync(d_ws, 0, zero_bytes, stream);
  k_token_prep<<<NB, 256, 0, stream>>>(mm, qf, gamma, beta, fusedb, mu, rstd);
  k_pilots<<<32, 256, 0, stream>>>(pe, pn);
  k_M<<<2048, 256, 0, stream>>>(qW, pn, M);
  k_smalls<<<39, 256, 0, stream>>>(eb1, sb1, eb2, sb2, gW, gb, qb, pn, b1_all, cvec, cr);
  k_transpose_bf16<<<dim3(64,32), 256, 0, stream>>>(qW, wqt, 2048, 1024);
  k_w1t<<<dim3(32,32,9), 256, 0, stream>>>(eW1, sW1, w1t);
  k_fold_w2<<<dim3(256,9), 256, 0, stream>>>(eW2, sW2, gW, w2t);
  k_qnorm<<<dim3(8,128), 256, 0, stream>>>(fusedb, wqt, qb, norm2);
  k_router<<<dim3(128,NCHUNK), 256, 0, stream>>>(mm, qf, gamma, beta, mu, rstd, M, u_part);
  k_scores<<<64, 256, 0, stream>>>(u_part, cr, norm2, idx2, w12, counts);
  k_prefix<<<1, 64, 0, stream>>>(counts, offs, cursor);
  k_fill<<<64, 256, 0, stream>>>(idx2, w12, cursor, tok_list, wt_list);
  k_gemm1<<<dim3(8,128,9), 256, 0, stream>>>(fusedb, w1t, b1_all, tok_list, offs, counts, h);
  k_gemm2<<<dim3(128,9), 256, 0, stream>>>(h, w2t, tok_list, wt_list, offs, counts, out_acc);
  k_final<<<4096, 256, 0, stream>>>(out_acc, cvec, idx2, w12, out);
}

// Round 3
// 660.851 us; speedup vs baseline: 1.3271x; 1.0646x over previous
//
#include <hip/hip_runtime.h>
#include <hip/hip_bf16.h>
#include <stdint.h>

typedef unsigned short u16;
typedef __attribute__((ext_vector_type(8))) short short8;
typedef __attribute__((ext_vector_type(4))) float f32x4;

#define NB 16384      // batch
#define NH 1024       // hidden
#define NSLOT 49152   // 2*NB routed slots + NB shared ("expert 8") slots
#define NCHUNK 4      // router split-K chunks (512 k each)

static __device__ __forceinline__ u16 f2bf(float f){
  union { float f; uint32_t u; } a; a.f = f;
  return (u16)((a.u + 0x7fffu + ((a.u >> 16) & 1u)) >> 16);   // RNE, matches __float2bfloat16
}

// async global->LDS, 16B per lane. LDS dest must be wave-uniform base + lane*16.
static __device__ __forceinline__ void gld16(const u16* gsrc, u16* lds){
  __builtin_amdgcn_global_load_lds((const __attribute__((address_space(1))) void*)gsrc,
                                   (__attribute__((address_space(3))) void*)lds, 16, 0, 0);
}

// ---------------------------------------------------------------- token prep
__global__ __launch_bounds__(256) void k_token_prep(
    const float* __restrict__ mm, const float* __restrict__ qf,
    const float* __restrict__ gamma, const float* __restrict__ beta,
    u16* __restrict__ fusedb, float* __restrict__ mu, float* __restrict__ rstd)
{
  int b = blockIdx.x, t = threadIdx.x;
  __shared__ float red[16];
  float4 v = ((const float4*)(mm + (size_t)b*NH))[t];
  float s = v.x+v.y+v.z+v.w;
  for (int o=32;o;o>>=1) s += __shfl_down(s,o);
  int wid = t>>6, lane = t&63;
  if (!lane) red[wid] = s;
  __syncthreads();
  if (t==0) red[8] = (red[0]+red[1]+red[2]+red[3]) * (1.0f/NH);
  __syncthreads();
  float mean = red[8];
  float4 d; d.x=v.x-mean; d.y=v.y-mean; d.z=v.z-mean; d.w=v.w-mean;
  float s2 = d.x*d.x+d.y*d.y+d.z*d.z+d.w*d.w;
  for (int o=32;o;o>>=1) s2 += __shfl_down(s2,o);
  if (!lane) red[4+wid] = s2;
  __syncthreads();
  if (t==0) red[9] = rsqrtf((red[4]+red[5]+red[6]+red[7])*(1.0f/NH) + 1e-5f);
  __syncthreads();
  float rs = red[9];
  if (t==0){ mu[b]=mean; rstd[b]=rs; }
  float4 g = ((const float4*)gamma)[t], be = ((const float4*)beta)[t];
  ushort4 ox;
  ox.x = f2bf(d.x*rs*g.x+be.x); ox.y = f2bf(d.y*rs*g.y+be.y);
  ox.z = f2bf(d.z*rs*g.z+be.z); ox.w = f2bf(d.w*rs*g.w+be.w);
  ((ushort4*)(fusedb + (size_t)b*2048))[t] = ox;
  float4 q = ((const float4*)(qf + (size_t)b*NH))[t];
  ushort4 oq; oq.x=f2bf(q.x); oq.y=f2bf(q.y); oq.z=f2bf(q.z); oq.w=f2bf(q.w);
  ((ushort4*)(fusedb + (size_t)b*2048 + 1024))[t] = oq;
}

// ---------------------------------------------------------------- pilots l2norm (fp64 norm)
__global__ __launch_bounds__(256) void k_pilots(const float* __restrict__ pe, float* __restrict__ pn)
{
  int ec = blockIdx.x, t = threadIdx.x;
  __shared__ double dred[8];
  float4 v = ((const float4*)(pe + (size_t)ec*NH))[t];
  double s2 = (double)v.x*v.x + (double)v.y*v.y + (double)v.z*v.z + (double)v.w*v.w;
  for (int o=32;o;o>>=1) s2 += __shfl_down(s2,o);
  int wid=t>>6, lane=t&63;
  if (!lane) dred[wid]=s2;
  __syncthreads();
  if (t==0) dred[4] = 1.0 / fmax(sqrt(dred[0]+dred[1]+dred[2]+dred[3]), 1e-12);
  __syncthreads();
  double inv = dred[4];
  float4 o; o.x=(float)(v.x*inv); o.y=(float)(v.y*inv); o.z=(float)(v.z*inv); o.w=(float)(v.w*inv);
  ((float4*)(pn + (size_t)ec*NH))[t] = o;
}

// ---------------------------------------------------------------- M = qproj_W @ pn^T   [2048][32] fp64
__global__ __launch_bounds__(256) void k_M(const float* __restrict__ W, const float* __restrict__ pn,
                                           double* __restrict__ M)
{
  int j = blockIdx.x;                    // 0..2047
  __shared__ float wrow[NH];
  __shared__ double part[256];
  for (int i=threadIdx.x;i<NH;i+=256) wrow[i] = W[(size_t)j*NH + i];
  __syncthreads();
  int ec = threadIdx.x>>3, seg = threadIdx.x&7;
  const float* p = pn + (size_t)ec*NH + seg*128;
  const float* wr = wrow + seg*128;
  double a = 0;
  #pragma unroll 8
  for (int i=0;i<128;i++) a += (double)wr[i]*(double)p[i];
  part[threadIdx.x] = a;
  __syncthreads();
  if (seg==0){
    double s=0;
    for (int i=0;i<8;i++) s += part[(ec<<3)+i];
    M[(size_t)j*32 + ec] = s;
  }
}

// ---------------------------------------------------------------- small precomputes
__global__ __launch_bounds__(256) void k_smalls(
    const float* eb1, const float* sb1, const float* eb2, const float* sb2,
    const float* gW, const float* gb, const float* qb, const float* pn,
    float* b1_all, float* cvec, double* cr)
{
  int idx = blockIdx.x*256 + threadIdx.x;
  if (idx < 9216){
    int e = idx>>10, k = idx&1023;
    b1_all[idx] = (e<8) ? eb1[idx] : sb1[k];
  } else if (idx < 9216+576){
    int i = idx-9216; int e = i>>6, n = i&63;
    float a = (e<8) ? 0.0f : gb[n];
    for (int j=0;j<64;j++){
      float bj = (e<8) ? eb2[e*64+j] : sb2[j];
      a += bj * gW[(((e<8)?j:64+j))*64 + n];
    }
    cvec[i] = a;
  } else if (idx < 9216+576+32){
    int ec = idx-9216-576;
    double a=0;
    for (int h=0;h<NH;h++) a += (double)qb[h]*(double)pn[(size_t)ec*NH+h];
    cr[ec] = a;
  }
}

// ---------------------------------------------------------------- f32->bf16 transpose: dst[n*K+k]=src[k*N+n]
__global__ __launch_bounds__(256) void k_transpose_bf16(const float* __restrict__ src, u16* __restrict__ dst,
                                                        int K, int N)
{
  __shared__ float tile[32][33];
  int k0 = blockIdx.x*32, n0 = blockIdx.y*32;
  int tx = threadIdx.x & 31, ty = threadIdx.x >> 5;
  for (int i=0;i<4;i++) tile[ty+i*8][tx] = src[(size_t)(k0+ty+i*8)*N + n0 + tx];
  __syncthreads();
  for (int i=0;i<4;i++) dst[(size_t)(n0+ty+i*8)*K + k0 + tx] = f2bf(tile[tx][ty+i*8]);
}

__global__ __launch_bounds__(256) void k_w1t(const float* __restrict__ eW1, const float* __restrict__ sW1,
                                             u16* __restrict__ w1t)
{
  __shared__ float tile[32][33];
  int e = blockIdx.z;
  const float* src = (e<8) ? eW1 + ((size_t)e<<20) : sW1;
  u16* dst = w1t + ((size_t)e<<20);
  int k0 = blockIdx.x*32, n0 = blockIdx.y*32;
  int tx = threadIdx.x & 31, ty = threadIdx.x >> 5;
  for (int i=0;i<4;i++) tile[ty+i*8][tx] = src[(size_t)(k0+ty+i*8)*NH + n0 + tx];
  __syncthreads();
  for (int i=0;i<4;i++) dst[(size_t)(n0+ty+i*8)*NH + k0 + tx] = f2bf(tile[tx][ty+i*8]);
}

__global__ __launch_bounds__(256) void k_fold_w2(const float* __restrict__ eW2, const float* __restrict__ sW2,
                                                 const float* __restrict__ gW, u16* __restrict__ w2t)
{
  __shared__ float gsh[64*64];
  int e = blockIdx.y;
  const float* src = (e<8) ? eW2 + (size_t)e*NH*64 : sW2;
  int rowbase = (e<8) ? 0 : 64;
  for (int i=threadIdx.x;i<64*64;i+=256) gsh[i] = gW[(size_t)(rowbase + (i>>6))*64 + (i&63)];
  __syncthreads();
  int flat = blockIdx.x*256 + threadIdx.x;      // over n*1024 + k
  int n = flat >> 10, k = flat & 1023;
  float acc = 0;
  #pragma unroll 8
  for (int j=0;j<64;j++) acc += src[(size_t)k*64 + j] * gsh[j*64 + n];
  w2t[(size_t)e*64*NH + flat] = f2bf(acc);
}

// ---------------------------------------------------------------- fp64 router GEMM (ordering-critical)
__global__ __launch_bounds__(256) void k_router(
    const float* __restrict__ mm, const float* __restrict__ qf,
    const float* __restrict__ gamma, const float* __restrict__ beta,
    const float* __restrict__ mu, const float* __restrict__ rstd,
    const double* __restrict__ M, double* __restrict__ u_part)
{
  __shared__ float At[16][130];
  __shared__ double Ms[16][32];
  int rb = blockIdx.x * 128;
  int kc = blockIdx.y * 512;
  bool isx = (kc < 1024);
  const float* src = isx ? mm : qf;
  int ksrc = isx ? kc : kc-1024;
  int t = threadIdx.x;
  int kk4 = (t&3)*4, rr = t>>2;
  int rg4 = t & 31, ec0 = (t>>5)*4;
  double acc[4][4] = {};

  for (int kb=0; kb<512; kb+=16){
    __syncthreads();
    float4 g4, b4;
    if (isx){ g4 = *(const float4*)(gamma + kc+kb+kk4); b4 = *(const float4*)(beta + kc+kb+kk4); }
    #pragma unroll
    for (int i=0;i<2;i++){
      int r = rr + i*64;
      float4 v = *(const float4*)(src + (size_t)(rb+r)*NH + ksrc + kb + kk4);
      if (isx){
        float m = mu[rb+r], rs = rstd[rb+r];
        v.x=(v.x-m)*rs*g4.x+b4.x; v.y=(v.y-m)*rs*g4.y+b4.y;
        v.z=(v.z-m)*rs*g4.z+b4.z; v.w=(v.w-m)*rs*g4.w+b4.w;
      }
      At[kk4+0][r]=v.x; At[kk4+1][r]=v.y; At[kk4+2][r]=v.z; At[kk4+3][r]=v.w;
    }
    const double* msrc = M + (size_t)(kc+kb)*32;
    ((double*)Ms)[t]     = msrc[t];
    ((double*)Ms)[256+t] = msrc[256+t];
    __syncthreads();
    #pragma unroll
    for (int kk=0; kk<16; kk++){
      float a4[4]; double m4[4];
      #pragma unroll
      for (int i=0;i<4;i++) a4[i] = At[kk][rg4 + 32*i];
      #pragma unroll
      for (int j=0;j<4;j++) m4[j] = Ms[kk][ec0+j];
      #pragma unroll
      for (int i=0;i<4;i++)
        #pragma unroll
        for (int j=0;j<4;j++) acc[i][j] = fma((double)a4[i], m4[j], acc[i][j]);
    }
  }
  double* dst = u_part + ((size_t)blockIdx.y*NB + rb)*32;
  #pragma unroll
  for (int i=0;i<4;i++){
    size_t row = (size_t)(rg4 + 32*i);
    #pragma unroll
    for (int j=0;j<4;j++) dst[row*32 + ec0 + j] = acc[i][j];
  }
}

// ---------------------------------------------------------------- qproj norm GEMM (bf16 MFMA, 128x256 tile)
__global__ __launch_bounds__(256,2) void k_qnorm(
    const u16* __restrict__ fusedb, const u16* __restrict__ wqt,
    const float* __restrict__ qb, float* __restrict__ norm2)
{
  __shared__ __align__(16) u16 As[128*32];
  __shared__ __align__(16) u16 Bs[256*32];
  int nb = blockIdx.x*256, mb = blockIdx.y*128;
  int t = threadIdx.x;
  int r0 = t>>2, c16 = (t&3)*8;
  const u16* ag0 = fusedb + (size_t)(mb+r0)*2048 + c16;
  const u16* ag1 = fusedb + (size_t)(mb+r0+64)*2048 + c16;
  const u16* bg0 = wqt + (size_t)(nb+r0)*2048 + c16;
  int wid=t>>6, lane=t&63, quad=lane>>4, lr=lane&15;
  int wm=(wid&1)*64, wn=(wid>>1)*128;
  f32x4 acc[4][8] = {};
  for (int kb=0;kb<2048;kb+=32){
    __syncthreads();
    gld16(ag0+kb, As + t*8); gld16(ag1+kb, As + 2048 + t*8);
    gld16(bg0+kb,          Bs + t*8);
    gld16(bg0+kb +  64*2048, Bs + 2048 + t*8);
    gld16(bg0+kb + 128*2048, Bs + 4096 + t*8);
    gld16(bg0+kb + 192*2048, Bs + 6144 + t*8);
    __syncthreads();
    short8 af[4], bf[8];
    #pragma unroll
    for (int i=0;i<4;i++) af[i] = *(const short8*)(As + (wm+i*16+lr)*32 + quad*8);
    #pragma unroll
    for (int j=0;j<8;j++) bf[j] = *(const short8*)(Bs + (wn+j*16+lr)*32 + quad*8);
    #pragma unroll
    for (int i=0;i<4;i++)
      #pragma unroll
      for (int j=0;j<8;j++)
        acc[i][j] = __builtin_amdgcn_mfma_f32_16x16x32_bf16(af[i], bf[j], acc[i][j], 0,0,0);
  }
  float qbv[8];
  #pragma unroll
  for (int j=0;j<8;j++) qbv[j] = qb[nb + wn + j*16 + lr];
  float rsum[4][4];
  #pragma unroll
  for (int i=0;i<4;i++)
    #pragma unroll
    for (int r=0;r<4;r++){
      float s=0;
      #pragma unroll
      for (int j=0;j<8;j++){
        float v = acc[i][j][r] + qbv[j];
        s += v*v;
      }
      rsum[i][r]=s;
    }
  #pragma unroll
  for (int m=1;m<16;m<<=1)
    #pragma unroll
    for (int i=0;i<4;i++)
      #pragma unroll
      for (int r=0;r<4;r++) rsum[i][r] += __shfl_xor(rsum[i][r], m);
  if (lr==0){
    #pragma unroll
    for (int i=0;i<4;i++)
      #pragma unroll
      for (int r=0;r<4;r++)
        unsafeAtomicAdd(&norm2[mb + wm + i*16 + quad*4 + r], rsum[i][r]);
  }
}

// ---------------------------------------------------------------- scores / softmax / top2 / counts
__global__ __launch_bounds__(256) void k_scores(
    const double* __restrict__ u_part, const double* __restrict__ cr, const float* __restrict__ norm2,
    int2* __restrict__ idx2, float2* __restrict__ w12, int* __restrict__ counts)
{
  __shared__ int lcnt[8];
  int t = threadIdx.x;
  if (t<8) lcnt[t]=0;
  __syncthreads();
  int b = blockIdx.x*256 + t;
  double s[8];
  #pragma unroll
  for (int e=0;e<8;e++) s[e] = cr[e*4]+cr[e*4+1]+cr[e*4+2]+cr[e*4+3];
  for (int c=0;c<NCHUNK;c++){
    const double* up = u_part + ((size_t)c*NB + b)*32;
    #pragma unroll
    for (int e=0;e<8;e++) s[e] += up[e*4]+up[e*4+1]+up[e*4+2]+up[e*4+3];
  }
  double inv = 0.25 / fmax(sqrt((double)norm2[b]), 1e-12);
  #pragma unroll
  for (int e=0;e<8;e++) s[e] *= inv;
  int e1 = 0;
  for (int e=1;e<8;e++) if (s[e] > s[e1]) e1 = e;
  int e2 = (e1==0) ? 1 : 0;
  for (int e=0;e<8;e++) if (e!=e1 && s[e] > s[e2]) e2 = e;
  double mx = s[e1], S = 0, p[8];
  #pragma unroll
  for (int e=0;e<8;e++){ p[e] = exp((s[e]-mx)*10.0); S += p[e]; }
  double P1 = p[e1]/S, P2 = p[e2]/S;
  double den = P1 + P2 + 1e-6;
  idx2[b] = make_int2(e1,e2);
  w12[b]  = make_float2((float)(P1/den), (float)(P2/den));
  atomicAdd(&lcnt[e1],1); atomicAdd(&lcnt[e2],1);
  __syncthreads();
  if (t<8) atomicAdd(&counts[t], lcnt[t]);
}

__global__ void k_prefix(const int* counts, int* offs, int* cursor){
  if (threadIdx.x==0 && blockIdx.x==0){
    int o=0;
    for (int e=0;e<8;e++){ offs[e]=o; cursor[e]=o; o+=counts[e]; }
    offs[8]=o;
  }
}

__global__ __launch_bounds__(256) void k_fill(const int2* __restrict__ idx2, const float2* __restrict__ w12,
                                              int* cursor, int* __restrict__ tok_list, float* __restrict__ wt_list)
{
  __shared__ int lc[8], base[8];
  int t = threadIdx.x;
  if (t<8) lc[t]=0;
  __syncthreads();
  int b = blockIdx.x*256 + t;
  int2 e = idx2[b]; float2 w = w12[b];
  int p1 = atomicAdd(&lc[e.x],1);
  int p2 = atomicAdd(&lc[e.y],1);
  __syncthreads();
  if (t<8) base[t] = atomicAdd(&cursor[t], lc[t]);
  __syncthreads();
  int s1 = base[e.x]+p1, s2 = base[e.y]+p2;
  tok_list[s1]=b; wt_list[s1]=w.x;
  tok_list[s2]=b; wt_list[s2]=w.y;
  tok_list[2*NB + b] = b; wt_list[2*NB + b] = 1.0f;
}

// ---------------------------------------------------------------- fused expert: out_acc += wt * relu(x@W1+b1) @ W2'
// 128 tokens x 256 n-cols per block; gemm2 fused via LDS h-chunks (C-layout -> A-frag round trip).
__global__ __launch_bounds__(256,2) void k_expert(
    const u16* __restrict__ fusedb, const u16* __restrict__ w1t, const float* __restrict__ b1_all,
    const u16* __restrict__ w2t,
    const int* __restrict__ tok_list, const float* __restrict__ wt_list,
    const int* __restrict__ offs, const int* __restrict__ counts,
    float* __restrict__ out_acc)
{
  int e = blockIdx.z;
  int cnt = (e<8) ? counts[e] : NB;
  int off = (e<8) ? offs[e]   : 2*NB;
  int mb = blockIdx.y * 128;
  if (mb >= cnt) return;
  int rem = cnt - mb;
  int nb = blockIdx.x * 256;
  __shared__ __align__(16) u16 As[128*32];
  __shared__ __align__(16) u16 Bs[256*32];
  __shared__ __align__(16) u16 B2[64*264];   // W2' slice [n2=64][k2 local=256], padded stride
  __shared__ __align__(16) u16 hl[128*72];   // h chunk [m=128][k2 local=64], padded stride
  int t = threadIdx.x;

  // stage W2' slice once: rows 0..63, cols nb..nb+256
  {
    const u16* wb2 = w2t + (size_t)e*64*NH + nb;
    #pragma unroll
    for (int s=0;s<8;s++){
      int flat = s*256 + t;             // 32 uint4 per row
      int row = flat>>5, c8 = (flat&31)*8;
      *(uint4*)(B2 + row*264 + c8) = *(const uint4*)(wb2 + (size_t)row*NH + c8);
    }
  }

  int r0 = t>>2, c16 = (t&3)*8;
  int r0c = r0    < rem ? r0    : rem-1;
  int r1c = r0+64 < rem ? r0+64 : rem-1;
  int tok0 = tok_list[off + mb + r0c];
  int tok1 = tok_list[off + mb + r1c];
  const u16* wbase = w1t + ((size_t)e<<20);
  const u16* ag0 = fusedb + (size_t)tok0*2048 + c16;   // x part: k in [0,1024)
  const u16* ag1 = fusedb + (size_t)tok1*2048 + c16;
  const u16* bg0 = wbase + (size_t)(nb+r0)*NH + c16;
  int wid=t>>6, lane=t&63, quad=lane>>4, lr=lane&15;
  int wm=(wid&1)*64, wn=(wid>>1)*128;
  f32x4 acc[4][8] = {};
  for (int kb=0;kb<1024;kb+=32){
    __syncthreads();
    gld16(ag0+kb, As + t*8); gld16(ag1+kb, As + 2048 + t*8);
    gld16(bg0+kb,           Bs + t*8);
    gld16(bg0+kb +  64*NH,  Bs + 2048 + t*8);
    gld16(bg0+kb + 128*NH,  Bs + 4096 + t*8);
    gld16(bg0+kb + 192*NH,  Bs + 6144 + t*8);
    __syncthreads();
    short8 af[4], bf[8];
    #pragma unroll
    for (int i=0;i<4;i++) af[i] = *(const short8*)(As + (wm+i*16+lr)*32 + quad*8);
    #pragma unroll
    for (int j=0;j<8;j++) bf[j] = *(const short8*)(Bs + (wn+j*16+lr)*32 + quad*8);
    #pragma unroll
    for (int i=0;i<4;i++)
      #pragma unroll
      for (int j=0;j<8;j++)
        acc[i][j] = __builtin_amdgcn_mfma_f32_16x16x32_bf16(af[i], bf[j], acc[i][j], 0,0,0);
  }

  // bias values for this wave's n columns
  float b1v[8];
  #pragma unroll
  for (int j=0;j<8;j++) b1v[j] = b1_all[e*NH + nb + wn + j*16 + lr];

  // fused gemm2: 4 chunks of 64 h-cols; h = relu(acc+b1) round-trips through LDS
  f32x4 acc2[2][4] = {};
  int myhalf = wn>>7;                    // wid 0,1 -> 0 ; wid 2,3 -> 1
  #pragma unroll
  for (int jj=0;jj<4;jj++){
    __syncthreads();
    if ((jj>>1) == myhalf){
      int j0 = (jj&1)*4;
      #pragma unroll
      for (int i=0;i<4;i++)
        #pragma unroll
        for (int j2=0;j2<4;j2++)
          #pragma unroll
          for (int reg=0;reg<4;reg++){
            float v = acc[i][j0+j2][reg] + b1v[j0+j2];
            hl[(wm+i*16+quad*4+reg)*72 + j2*16 + lr] = f2bf(fmaxf(v,0.0f));
          }
    }
    __syncthreads();
    #pragma unroll
    for (int kk=0;kk<2;kk++){
      short8 a2[2], b2f[4];
      #pragma unroll
      for (int i2=0;i2<2;i2++)
        a2[i2] = *(const short8*)(hl + (wid*32+i2*16+lr)*72 + kk*32 + quad*8);
      #pragma unroll
      for (int j2=0;j2<4;j2++)
        b2f[j2] = *(const short8*)(B2 + (j2*16+lr)*264 + jj*64 + kk*32 + quad*8);
      #pragma unroll
      for (int i2=0;i2<2;i2++)
        #pragma unroll
        for (int j2=0;j2<4;j2++)
          acc2[i2][j2] = __builtin_amdgcn_mfma_f32_16x16x32_bf16(a2[i2], b2f[j2], acc2[i2][j2], 0,0,0);
    }
  }

  // weighted scatter-add into out_acc
  #pragma unroll
  for (int i2=0;i2<2;i2++)
    #pragma unroll
    for (int reg=0;reg<4;reg++){
      int m = wid*32 + i2*16 + quad*4 + reg;
      if (m < rem){
        int slot = off + mb + m;
        int tok = tok_list[slot];
        float w = wt_list[slot];
        float* dst = out_acc + (size_t)tok*64;
        #pragma unroll
        for (int j2=0;j2<4;j2++)
          unsafeAtomicAdd(dst + j2*16 + lr, w * acc2[i2][j2][reg]);
      }
    }
}

// ---------------------------------------------------------------- final: + folded biases, sigmoid
__global__ __launch_bounds__(256) void k_final(
    const float* __restrict__ out_acc, const float* __restrict__ cvec,
    const int2* __restrict__ idx2, const float2* __restrict__ w12, float* __restrict__ out)
{
  int i = blockIdx.x*256 + threadIdx.x;
  int b = i>>6, n = i&63;
  int2 e = idx2[b]; float2 w = w12[b];
  float v = out_acc[i] + w.x*cvec[e.x*64+n] + w.y*cvec[e.y*64+n] + cvec[8*64+n];
  out[i] = 1.0f / (1.0f + expf(-v));
}

// ================================================================ launch
extern "C" void kernel_launch(void* const* d_in, const int* in_sizes, int n_in,
                              void* d_out, int out_size, void* d_ws, size_t ws_size,
                              hipStream_t stream)
{
  (void)in_sizes; (void)n_in; (void)out_size; (void)ws_size;
  const float* mm   =(const float*)d_in[0];
  const float* qf   =(const float*)d_in[1];
  const float* gamma=(const float*)d_in[2];
  const float* beta =(const float*)d_in[3];
  const float* pe   =(const float*)d_in[4];
  const float* qW   =(const float*)d_in[5];
  const float* qb   =(const float*)d_in[6];
  const float* eW1  =(const float*)d_in[7];
  const float* eb1  =(const float*)d_in[8];
  const float* eW2  =(const float*)d_in[9];
  const float* eb2  =(const float*)d_in[10];
  const float* sW1  =(const float*)d_in[11];
  const float* sb1  =(const float*)d_in[12];
  const float* sW2  =(const float*)d_in[13];
  const float* sb2  =(const float*)d_in[14];
  const float* gW   =(const float*)d_in[15];
  const float* gb   =(const float*)d_in[16];
  float* out = (float*)d_out;

  char* p = (char*)d_ws;
  auto alloc = [&](size_t bytes)->char*{ char* r = p; p += (bytes + 255) & ~(size_t)255; return r; };
  // zero-init region (one memset)
  float*  out_acc = (float*) alloc((size_t)NB*64*4);
  float*  norm2   = (float*) alloc((size_t)NB*4);
  int*    counts  = (int*)   alloc(64);
  int*    cursor  = (int*)   alloc(64);
  int*    offs    = (int*)   alloc(64);
  size_t zero_bytes = (size_t)(p - (char*)d_ws);
  // rest (fully overwritten every call)
  double* u_part  = (double*)alloc((size_t)NCHUNK*NB*32*8);
  u16*    fusedb  = (u16*)   alloc((size_t)NB*2048*2);
  u16*    w1t     = (u16*)   alloc((size_t)9*NH*NH*2);
  u16*    wqt     = (u16*)   alloc((size_t)NH*2048*2);
  u16*    w2t     = (u16*)   alloc((size_t)9*64*NH*2);
  float*  b1_all  = (float*) alloc((size_t)9*NH*4);
  float*  cvec    = (float*) alloc((size_t)9*64*4);
  double* M       = (double*)alloc((size_t)2048*32*8);
  float*  pn      = (float*) alloc((size_t)32*NH*4);
  double* cr      = (double*)alloc(32*8);
  float*  mu      = (float*) alloc((size_t)NB*4);
  float*  rstd    = (float*) alloc((size_t)NB*4);
  int2*   idx2    = (int2*)  alloc((size_t)NB*8);
  float2* w12     = (float2*)alloc((size_t)NB*8);
  int*    tok_list= (int*)   alloc((size_t)NSLOT*4);
  float*  wt_list = (float*) alloc((size_t)NSLOT*4);

  hipMemsetAsync(d_ws, 0, zero_bytes, stream);
  k_token_prep<<<NB, 256, 0, stream>>>(mm, qf, gamma, beta, fusedb, mu, rstd);
  k_pilots<<<32, 256, 0, stream>>>(pe, pn);
  k_M<<<2048, 256, 0, stream>>>(qW, pn, M);
  k_smalls<<<39, 256, 0, stream>>>(eb1, sb1, eb2, sb2, gW, gb, qb, pn, b1_all, cvec, cr);
  k_transpose_bf16<<<dim3(64,32), 256, 0, stream>>>(qW, wqt, 2048, 1024);
  k_w1t<<<dim3(32,32,9), 256, 0, stream>>>(eW1, sW1, w1t);
  k_fold_w2<<<dim3(256,9), 256, 0, stream>>>(eW2, sW2, gW, w2t);
  k_qnorm<<<dim3(4,128), 256, 0, stream>>>(fusedb, wqt, qb, norm2);
  k_router<<<dim3(128,NCHUNK), 256, 0, stream>>>(mm, qf, gamma, beta, mu, rstd, M, u_part);
  k_scores<<<64, 256, 0, stream>>>(u_part, cr, norm2, idx2, w12, counts);
  k_prefix<<<1, 64, 0, stream>>>(counts, offs, cursor);
  k_fill<<<64, 256, 0, stream>>>(idx2, w12, cursor, tok_list, wt_list);
  k_expert<<<dim3(4,128,9), 256, 0, stream>>>(fusedb, w1t, b1_all, w2t, tok_list, wt_list, offs, counts, out_acc);
  k_final<<<4096, 256, 0, stream>>>(out_acc, cvec, idx2, w12, out);
}